// Round 5
// baseline (140.524 us; speedup 1.0000x reference)
//
#include <hip/hip_runtime.h>
#include <cstdint>
#include <cstddef>

// B=32, S=2048, P=256, N=256, K=8, L=4, M_out=1024
// out[b,t,n] = (A @ x_b)[t,n] + mean[b,n]*(1 - rowsumA[t]) + b_enc[t>>8]*std[b,n]
// where A[l*256+q, k*256+p] = W_enc[l,k] * (W^(8-k+l))[q,p].
// A never materialized: GEMM stages bf16 W-powers (L2-resident) and applies
// W_enc as an fp32 per-segment accumulator scale. X is RAW x (transposed,
// bf16) -- normalization affine-folded into the epilogue.
// R4 bug fixed here: A-stage column is ((kt&3)*64 + h*32), NOT kt*64 --
// powers are 256 wide; kt*64 walked into the next power slot for kt>=4.

typedef unsigned short ushort_t;
typedef unsigned int uint_t;
typedef __attribute__((ext_vector_type(8))) short bf16x8;
typedef __attribute__((ext_vector_type(16))) float f32x16;

__device__ __forceinline__ ushort_t f32_to_bf16(float f) {
    uint_t u = __float_as_uint(f);
    u += 0x7FFFu + ((u >> 16) & 1u);   // RNE (finite values only here)
    return (ushort_t)(u >> 16);
}
__device__ __forceinline__ float bf16_to_f32(ushort_t h) {
    return __uint_as_float((uint_t)h << 16);
}

// ---------------- W powers: C = A * B for up to 4 (slot) triples ----------------
struct PowOps { int sa[4]; int sb[4]; int sd[4]; };

__global__ void powmul(float* __restrict__ Pw, PowOps ops) {
    __shared__ float As[4 * 256];
    const int mat = blockIdx.x;
    const int r0  = blockIdx.y * 4;      // 64 row-blocks of 4
    const int tid = threadIdx.x;         // 256
    const float* A  = Pw + (size_t)ops.sa[mat] * 65536;
    const float* Bm = Pw + (size_t)ops.sb[mat] * 65536;
    float* C        = Pw + (size_t)ops.sd[mat] * 65536;
#pragma unroll
    for (int i = 0; i < 4; ++i) As[i * 256 + tid] = A[(size_t)(r0 + i) * 256 + tid];
    __syncthreads();
    float a0 = 0.f, a1 = 0.f, a2 = 0.f, a3 = 0.f;
    for (int p = 0; p < 256; p += 8) {
        float bv[8];
#pragma unroll
        for (int u = 0; u < 8; ++u) bv[u] = Bm[(size_t)(p + u) * 256 + tid];
#pragma unroll
        for (int u = 0; u < 8; ++u) {
            a0 += As[0 * 256 + p + u] * bv[u];
            a1 += As[1 * 256 + p + u] * bv[u];
            a2 += As[2 * 256 + p + u] * bv[u];
            a3 += As[3 * 256 + p + u] * bv[u];
        }
    }
    C[(size_t)(r0 + 0) * 256 + tid] = a0;
    C[(size_t)(r0 + 1) * 256 + tid] = a1;
    C[(size_t)(r0 + 2) * 256 + tid] = a2;
    C[(size_t)(r0 + 3) * 256 + tid] = a3;
}

// ---------------- fused: convert powers to bf16 + row sums of bf16 powers ----------------
// grid (11, 4), block 256. thread: row q = rq*64 + (t>>2), quarter c = t&3.
__global__ void convRS(const float* __restrict__ Pw, ushort_t* __restrict__ Pb,
                       float* __restrict__ prs) {
    const int m  = blockIdx.x;
    const int rq = blockIdx.y;
    const int t  = threadIdx.x;
    const int q  = rq * 64 + (t >> 2);
    const int c  = t & 3;
    const float4* src = (const float4*)(Pw + (size_t)m * 65536 + q * 256 + c * 64);
    uint2* dst        = (uint2*)(Pb + (size_t)m * 65536 + q * 256 + c * 64);
    float s = 0.f;
#pragma unroll
    for (int i = 0; i < 16; ++i) {
        const float4 v = src[i];
        const ushort_t h0 = f32_to_bf16(v.x), h1 = f32_to_bf16(v.y);
        const ushort_t h2 = f32_to_bf16(v.z), h3 = f32_to_bf16(v.w);
        s += bf16_to_f32(h0) + bf16_to_f32(h1) + bf16_to_f32(h2) + bf16_to_f32(h3);
        uint2 o; o.x = (uint_t)h0 | ((uint_t)h1 << 16); o.y = (uint_t)h2 | ((uint_t)h3 << 16);
        dst[i] = o;
    }
    s += __shfl_xor(s, 1);
    s += __shfl_xor(s, 2);
    if (c == 0) prs[m * 256 + q] = s;
}

// ---------------- fused: rowsumA (blocks 0..3) + stats_final (blocks 4..35) ----------------
__global__ void finalize(const float* __restrict__ prs, const float* __restrict__ Wenc,
                         float* __restrict__ rsA,
                         const float* __restrict__ ps1, const float* __restrict__ ps2,
                         float* __restrict__ meanv, float* __restrict__ stdv) {
    const int t = threadIdx.x;
    if (blockIdx.x < 4) {
        const int l = blockIdx.x;
        float s = 0.f;
#pragma unroll
        for (int k = 0; k < 8; ++k) s += Wenc[l * 8 + k] * prs[(l + 7 - k) * 256 + t];
        rsA[l * 256 + t] = s;
    } else {
        const int b = blockIdx.x - 4;
        float s = 0.f, q = 0.f;
#pragma unroll
        for (int st = 0; st < 32; ++st) {
            s += ps1[(size_t)st * 8192 + b * 256 + t];
            q += ps2[(size_t)st * 8192 + b * 256 + t];
        }
        const float mean = s * (1.0f / 2048.0f);
        float var = q * (1.0f / 2048.0f) - mean * mean;
        var = fmaxf(var, 0.0f);
        meanv[b * 256 + t] = mean;
        stdv [b * 256 + t] = sqrtf(var + 1e-5f);
    }
}

// ---------------- transpose RAW x + bf16 convert + stats partials ----------------
__global__ void transpose_stats(const float* __restrict__ x, ushort_t* __restrict__ Xt,
                                float* __restrict__ ps1, float* __restrict__ ps2) {
    __shared__ float lds[64 * 65];
    __shared__ float red1[16 * 64];
    __shared__ float red2[16 * 64];
    const int st = blockIdx.x;                     // s-tile 0..31
    const int nt = blockIdx.y;                     // n-tile 0..3
    const int b  = blockIdx.z;                     // 0..31
    const int tid = threadIdx.x;
    const int c = tid & 15, r = tid >> 4;
    const int s0 = st * 64;
    float s1[4] = {0,0,0,0}, s2[4] = {0,0,0,0};
#pragma unroll
    for (int it = 0; it < 4; ++it) {
        const int ii = r + it * 16;
        const float4 v = *(const float4*)(x + ((size_t)b * 2048 + s0 + ii) * 256 + nt * 64 + c * 4);
        const float vv[4] = {v.x, v.y, v.z, v.w};
#pragma unroll
        for (int j = 0; j < 4; ++j) {
            lds[ii * 65 + c * 4 + j] = vv[j];
            s1[j] += vv[j]; s2[j] += vv[j] * vv[j];
        }
    }
#pragma unroll
    for (int j = 0; j < 4; ++j) { red1[r * 64 + c * 4 + j] = s1[j]; red2[r * 64 + c * 4 + j] = s2[j]; }
    __syncthreads();
    if (tid < 64) {
        float a = 0.f, q = 0.f;
#pragma unroll
        for (int rr = 0; rr < 16; ++rr) { a += red1[rr * 64 + tid]; q += red2[rr * 64 + tid]; }
        const size_t o = (size_t)st * 8192 + b * 256 + nt * 64 + tid;
        ps1[o] = a; ps2[o] = q;
    }
#pragma unroll
    for (int step = 0; step < 8; ++step) {
        const int npr = step * 8 + (tid >> 5);
        const int sp  = (tid & 31) * 2;
        const float f0 = lds[sp * 65 + npr];
        const float f1 = lds[(sp + 1) * 65 + npr];
        const uint_t packed = (uint_t)f32_to_bf16(f0) | ((uint_t)f32_to_bf16(f1) << 16);
        *(uint_t*)(Xt + ((size_t)b * 256 + nt * 64 + npr) * 2048 + s0 + sp) = packed;
    }
}

// ---------------- GEMM: 4-phase pipelined, counted vmcnt ----------------
// BM=256 (one full l), BN=128, BK=64 as 2 K-halves of 32. 8 waves (4M x 2N).
// LDS: sA[buf][half][256*32], sX[buf][half][128*32]; 16B-chunk XOR swizzle
// within 64B rows (ch = kchunk ^ (row&3)); pre-swizzled global source.
#define GLOAD_LDS16(gsrc, ldst) \
    __builtin_amdgcn_global_load_lds((const __attribute__((address_space(1))) void*)(gsrc), \
                                     (__attribute__((address_space(3))) void*)(ldst), 16, 0, 0)

__global__ __launch_bounds__(512, 1) void gemm_kernel(
    const ushort_t* __restrict__ Pb,     // 11 * 65536 bf16 powers
    const ushort_t* __restrict__ Xt,     // [8192][2048] bf16 (raw x, transposed)
    const float* __restrict__ Wenc,
    const float* __restrict__ meanv, const float* __restrict__ stdv,
    const float* __restrict__ rsA, const float* __restrict__ benc,
    float* __restrict__ out)
{
    __shared__ ushort_t sA[2 * 2 * 8192];   // 64 KB
    __shared__ ushort_t sX[2 * 2 * 4096];   // 32 KB

    // XCD swizzle: each XCD owns 8 bx-slices across all 4 l's.
    const int flat = blockIdx.x;            // 0..255
    const int xcd  = flat & 7;
    const int idx  = flat >> 3;             // 0..31
    const int bx   = xcd + ((idx & 7) << 3);// 0..63
    const int l    = idx >> 3;              // 0..3

    const int tid  = threadIdx.x;
    const int lane = tid & 63;
    const int w    = tid >> 6;              // 0..7
    const int wm   = w >> 1, wn = w & 1;
    const int li   = lane & 31, lg = lane >> 5;

    // staging per-lane invariants (pre-swizzled global source)
    const int roff = lane >> 2;                   // row within 16-row instr
    const int kc   = (lane & 3) ^ (roff & 3);     // swizzled 8-elem k-chunk
    const int aoff = roff * 256 + kc * 8;
    const int xoff = roff * 2048 + kc * 8;

    const ushort_t* xb = Xt + (size_t)bx * 128 * 2048;

#define STAGE_H(bf_, kt_, h_) do { \
    const int slot_ = l + 7 - ((kt_) >> 2); \
    const ushort_t* ap_ = Pb + (size_t)slot_ * 65536 + ((kt_) & 3) * 64 + (h_) * 32 + aoff; \
    const ushort_t* xp_ = xb + (kt_) * 64 + (h_) * 32 + xoff; \
    ushort_t* sa_ = sA + ((bf_) * 2 + (h_)) * 8192; \
    ushort_t* sx_ = sX + ((bf_) * 2 + (h_)) * 4096; \
    GLOAD_LDS16(ap_ + (w * 32 + 0)  * 256, sa_ + (w * 32 + 0)  * 32); \
    GLOAD_LDS16(ap_ + (w * 32 + 16) * 256, sa_ + (w * 32 + 16) * 32); \
    GLOAD_LDS16(xp_ + (size_t)(w * 16) * 2048, sx_ + (w * 16) * 32); \
} while (0)

#define PHASE(cur_, ks_, STAGEOPS, VMNT) do { \
    const ushort_t* pa_ = sA + ((cur_) * 2 + ((ks_) >> 1)) * 8192; \
    const ushort_t* px_ = sX + ((cur_) * 2 + ((ks_) >> 1)) * 4096; \
    const int ch_ = (((ks_) & 1) * 2 + lg) ^ (li & 3); \
    const bf16x8 af0 = *(const bf16x8*)(pa_ + (wm * 64 +  0 + li) * 32 + ch_ * 8); \
    const bf16x8 af1 = *(const bf16x8*)(pa_ + (wm * 64 + 32 + li) * 32 + ch_ * 8); \
    const bf16x8 xf0 = *(const bf16x8*)(px_ + (wn * 64 +  0 + li) * 32 + ch_ * 8); \
    const bf16x8 xf1 = *(const bf16x8*)(px_ + (wn * 64 + 32 + li) * 32 + ch_ * 8); \
    STAGEOPS; \
    VMNT; \
    asm volatile("" ::: "memory"); \
    __builtin_amdgcn_s_barrier(); \
    __builtin_amdgcn_s_setprio(1); \
    acc2[0][0] = __builtin_amdgcn_mfma_f32_32x32x16_bf16(af0, xf0, acc2[0][0], 0, 0, 0); \
    acc2[0][1] = __builtin_amdgcn_mfma_f32_32x32x16_bf16(af0, xf1, acc2[0][1], 0, 0, 0); \
    acc2[1][0] = __builtin_amdgcn_mfma_f32_32x32x16_bf16(af1, xf0, acc2[1][0], 0, 0, 0); \
    acc2[1][1] = __builtin_amdgcn_mfma_f32_32x32x16_bf16(af1, xf1, acc2[1][1], 0, 0, 0); \
    __builtin_amdgcn_s_setprio(0); \
    asm volatile("" ::: "memory"); \
    __builtin_amdgcn_s_barrier(); \
    asm volatile("" ::: "memory"); \
} while (0)

    f32x16 acc[2][2], acc2[2][2];
#pragma unroll
    for (int mm = 0; mm < 2; ++mm)
#pragma unroll
        for (int nn = 0; nn < 2; ++nn)
#pragma unroll
            for (int rr = 0; rr < 16; ++rr) { acc[mm][nn][rr] = 0.0f; acc2[mm][nn][rr] = 0.0f; }

    // prologue: stage kt=0 both halves; drain h0 (keep h1 in flight)
    STAGE_H(0, 0, 0);
    STAGE_H(0, 0, 1);
    asm volatile("s_waitcnt vmcnt(3)" ::: "memory");
    __builtin_amdgcn_s_barrier();
    asm volatile("" ::: "memory");

#pragma unroll 1
    for (int kt = 0; kt < 32; ++kt) {
        const int cur = kt & 1;
        if (kt < 31) {
            PHASE(cur, 0, STAGE_H(cur ^ 1, kt + 1, 0), );
            PHASE(cur, 1, STAGE_H(cur ^ 1, kt + 1, 1),
                  asm volatile("s_waitcnt vmcnt(6)" ::: "memory"));
            PHASE(cur, 2, , );
            PHASE(cur, 3, , asm volatile("s_waitcnt vmcnt(3)" ::: "memory"));
        } else {
            PHASE(cur, 0, , );
            PHASE(cur, 1, , asm volatile("s_waitcnt vmcnt(0)" ::: "memory"));
            PHASE(cur, 2, , );
            PHASE(cur, 3, , );
        }
        if ((kt & 3) == 3) {
            const float wk = Wenc[l * 8 + (kt >> 2)];   // uniform scalar load
#pragma unroll
            for (int mm = 0; mm < 2; ++mm)
#pragma unroll
                for (int nn = 0; nn < 2; ++nn)
#pragma unroll
                    for (int rr = 0; rr < 16; ++rr) {
                        acc[mm][nn][rr] += wk * acc2[mm][nn][rr];
                        acc2[mm][nn][rr] = 0.0f;
                    }
        }
    }
#undef PHASE
#undef STAGE_H

    // epilogue: out = acc + mean*(1-rowsumA) + benc[l]*std
    const float be = benc[l];
    float sd[2], mn[2];
#pragma unroll
    for (int nn = 0; nn < 2; ++nn) {
        const int col = bx * 128 + wn * 64 + nn * 32 + li;   // 0..8191
        sd[nn] = stdv [col];
        mn[nn] = meanv[col];
    }
#pragma unroll
    for (int mm = 0; mm < 2; ++mm)
#pragma unroll
        for (int nn = 0; nn < 2; ++nn) {
            const int col = bx * 128 + wn * 64 + nn * 32 + li;
            const int bq = col >> 8, nq = col & 255;
            const float ben = be * sd[nn];
#pragma unroll
            for (int rr = 0; rr < 16; ++rr) {
                const int row = l * 256 + wm * 64 + mm * 32 + ((rr & 3) + 8 * (rr >> 2) + 4 * lg);
                const float rs = rsA[row];
                out[((size_t)bq * 1024 + row) * 256 + nq] =
                    acc[mm][nn][rr] + mn[nn] * (1.0f - rs) + ben;
            }
        }
}

// ---------------- launch ----------------
extern "C" void kernel_launch(void* const* d_in, const int* in_sizes, int n_in,
                              void* d_out, int out_size, void* d_ws, size_t ws_size,
                              hipStream_t stream) {
    (void)in_sizes; (void)n_in; (void)out_size; (void)ws_size;
    const float* x_enc  = (const float*)d_in[0];
    const float* W_base = (const float*)d_in[4];
    const float* W_enc  = (const float*)d_in[5];
    const float* b_enc  = (const float*)d_in[6];
    float* out = (float*)d_out;

    char* ws = (char*)d_ws;
    float*    wsP    = (float*)(ws);                 // 11*65536 f32 powers
    ushort_t* wsPb   = (ushort_t*)(ws + 0x300000);   // 11*65536 bf16
    float*    wsPrs  = (float*)(ws + 0x480000);      // 11*256 f32
    float*    wsRsA  = (float*)(ws + 0x490000);      // 1024 f32
    float*    wsS1   = (float*)(ws + 0x4A0000);      // 32*8192 f32
    float*    wsS2   = (float*)(ws + 0x5A0000);
    float*    wsMean = (float*)(ws + 0x6A0000);      // 8192 f32
    float*    wsStd  = (float*)(ws + 0x6B0000);
    ushort_t* wsXt   = (ushort_t*)(ws + 0x700000);   // [8192][2048] bf16 (32 MB)

    hipMemcpyAsync(wsP, W_base, 256 * 256 * sizeof(float), hipMemcpyDeviceToDevice, stream);

    // powers: slot m-1 = W^m
    { PowOps o{{0, 0, 0, 0}, {0, 0, 0, 0}, {1, 0, 0, 0}};            // W2
      powmul<<<dim3(1, 64), 256, 0, stream>>>(wsP, o); }
    { PowOps o{{1, 1, 0, 0}, {0, 1, 0, 0}, {2, 3, 0, 0}};            // W3,W4
      powmul<<<dim3(2, 64), 256, 0, stream>>>(wsP, o); }
    { PowOps o{{3, 3, 3, 3}, {0, 1, 2, 3}, {4, 5, 6, 7}};            // W5..W8
      powmul<<<dim3(4, 64), 256, 0, stream>>>(wsP, o); }
    { PowOps o{{7, 7, 7, 0}, {0, 1, 2, 0}, {8, 9, 10, 0}};           // W9..W11
      powmul<<<dim3(3, 64), 256, 0, stream>>>(wsP, o); }

    convRS<<<dim3(11, 4), 256, 0, stream>>>(wsP, wsPb, wsPrs);

    transpose_stats<<<dim3(32, 4, 32), 256, 0, stream>>>(x_enc, wsXt, wsS1, wsS2);
    finalize<<<36, 256, 0, stream>>>(wsPrs, W_enc, wsRsA, wsS1, wsS2, wsMean, wsStd);

    gemm_kernel<<<dim3(256), 512, 0, stream>>>(wsPb, wsXt, W_enc, wsMean, wsStd,
                                               wsRsA, b_enc, out);
}

// Round 6
// 117.964 us; speedup vs baseline: 1.1912x; 1.1912x over previous
//
#include <hip/hip_runtime.h>
#include <cstdint>
#include <cstddef>

// B=32, S=2048, P=256, N=256, K=8, L=4, M_out=1024
// out[b,t,n] = (A @ x_b)[t,n] + mean[b,n]*(1 - rowsumA[t]) + b_enc[t>>8]*std[b,n]
// A[l*256+q, k*256+p] = W_enc[l,k] * (W^(8-k+l))[q,p], materialized in bf16 (4MB).
// X is RAW x transposed to [b*256+n][s] bf16; normalization affine-folded into
// the epilogue (mean/std finalized inside the GEMM from partials).
//
// LDS macro-row layout (both A and X tiles): row R, 8-elem chunk c stored at
//   byte = (R>>1)*128 + (R&1)*64 + (c ^ ((R>>1)&3))*16
// -> global_load_lds-compatible (linear 1KB per instr, source pre-swizzled) and
//    fragment ds_read_b128 spreads 32 lanes over all 8 16B slots (minimal).

typedef unsigned short ushort_t;
typedef unsigned int uint_t;
typedef __attribute__((ext_vector_type(8))) short bf16x8;
typedef __attribute__((ext_vector_type(16))) float f32x16;

__device__ __forceinline__ ushort_t f32_to_bf16(float f) {
    uint_t u = __float_as_uint(f);
    u += 0x7FFFu + ((u >> 16) & 1u);   // RNE (finite values only here)
    return (ushort_t)(u >> 16);
}
__device__ __forceinline__ float bf16_to_f32(ushort_t h) {
    return __uint_as_float((uint_t)h << 16);
}

// ---------------- W powers: C = A * B for up to 4 (slot) triples ----------------
struct PowOps { int sa[4]; int sb[4]; int sd[4]; };

__global__ void powmul(float* __restrict__ Pw, PowOps ops) {
    __shared__ float As[4 * 256];
    const int mat = blockIdx.x;
    const int r0  = blockIdx.y * 4;      // 64 row-blocks of 4
    const int tid = threadIdx.x;         // 256
    const float* A  = Pw + (size_t)ops.sa[mat] * 65536;
    const float* Bm = Pw + (size_t)ops.sb[mat] * 65536;
    float* C        = Pw + (size_t)ops.sd[mat] * 65536;
#pragma unroll
    for (int i = 0; i < 4; ++i) As[i * 256 + tid] = A[(size_t)(r0 + i) * 256 + tid];
    __syncthreads();
    float a0 = 0.f, a1 = 0.f, a2 = 0.f, a3 = 0.f;
    for (int p = 0; p < 256; p += 8) {
        float bv[8];
#pragma unroll
        for (int u = 0; u < 8; ++u) bv[u] = Bm[(size_t)(p + u) * 256 + tid];
#pragma unroll
        for (int u = 0; u < 8; ++u) {
            a0 += As[0 * 256 + p + u] * bv[u];
            a1 += As[1 * 256 + p + u] * bv[u];
            a2 += As[2 * 256 + p + u] * bv[u];
            a3 += As[3 * 256 + p + u] * bv[u];
        }
    }
    C[(size_t)(r0 + 0) * 256 + tid] = a0;
    C[(size_t)(r0 + 1) * 256 + tid] = a1;
    C[(size_t)(r0 + 2) * 256 + tid] = a2;
    C[(size_t)(r0 + 3) * 256 + tid] = a3;
}

// ---------------- build scaled A (bf16) + rowsums of the ROUNDED A ----------------
// grid 1024 (one block per t-row), block 256.
__global__ void buildA(const float* __restrict__ Pw, const float* __restrict__ Wenc,
                       ushort_t* __restrict__ Ah, float* __restrict__ rsA) {
    __shared__ float red[4];
    const int t = blockIdx.x;            // 0..1023
    const int l = t >> 8, q = t & 255;
    const int c = threadIdx.x;           // 0..255
    float part = 0.f;
#pragma unroll
    for (int k = 0; k < 8; ++k) {
        const int m = 8 - k + l;         // 1..11 ; Pw slot m-1 (slot0 = W^1)
        const float val = Wenc[l * 8 + k] * Pw[(size_t)(m - 1) * 65536 + q * 256 + c];
        const ushort_t h = f32_to_bf16(val);
        Ah[(size_t)t * 2048 + k * 256 + c] = h;
        part += bf16_to_f32(h);
    }
#pragma unroll
    for (int off = 32; off > 0; off >>= 1) part += __shfl_xor(part, off);
    if ((c & 63) == 0) red[c >> 6] = part;
    __syncthreads();
    if (c == 0) rsA[t] = red[0] + red[1] + red[2] + red[3];
}

// ---------------- transpose RAW x + bf16 convert + stats partials ----------------
__global__ void transpose_stats(const float* __restrict__ x, ushort_t* __restrict__ Xt,
                                float* __restrict__ ps1, float* __restrict__ ps2) {
    __shared__ float lds[64 * 65];
    __shared__ float red1[16 * 64];
    __shared__ float red2[16 * 64];
    const int st = blockIdx.x;                     // s-tile 0..31
    const int nt = blockIdx.y;                     // n-tile 0..3
    const int b  = blockIdx.z;                     // 0..31
    const int tid = threadIdx.x;
    const int c = tid & 15, r = tid >> 4;
    const int s0 = st * 64;
    float s1[4] = {0,0,0,0}, s2[4] = {0,0,0,0};
#pragma unroll
    for (int it = 0; it < 4; ++it) {
        const int ii = r + it * 16;
        const float4 v = *(const float4*)(x + ((size_t)b * 2048 + s0 + ii) * 256 + nt * 64 + c * 4);
        const float vv[4] = {v.x, v.y, v.z, v.w};
#pragma unroll
        for (int j = 0; j < 4; ++j) {
            lds[ii * 65 + c * 4 + j] = vv[j];
            s1[j] += vv[j]; s2[j] += vv[j] * vv[j];
        }
    }
#pragma unroll
    for (int j = 0; j < 4; ++j) { red1[r * 64 + c * 4 + j] = s1[j]; red2[r * 64 + c * 4 + j] = s2[j]; }
    __syncthreads();
    if (tid < 64) {
        float a = 0.f, q = 0.f;
#pragma unroll
        for (int rr = 0; rr < 16; ++rr) { a += red1[rr * 64 + tid]; q += red2[rr * 64 + tid]; }
        const size_t o = (size_t)st * 8192 + b * 256 + nt * 64 + tid;
        ps1[o] = a; ps2[o] = q;
    }
#pragma unroll
    for (int step = 0; step < 8; ++step) {
        const int npr = step * 8 + (tid >> 5);
        const int sp  = (tid & 31) * 2;
        const float f0 = lds[sp * 65 + npr];
        const float f1 = lds[(sp + 1) * 65 + npr];
        const uint_t packed = (uint_t)f32_to_bf16(f0) | ((uint_t)f32_to_bf16(f1) << 16);
        *(uint_t*)(Xt + ((size_t)b * 256 + nt * 64 + npr) * 2048 + s0 + sp) = packed;
    }
}

// ---------------- GEMM: 2 fat phases per kt, counted vmcnt, macro-row LDS ----------------
// BM=128, BN=256, BK=64 as 2 halves of 32. 8 waves (2M x 4N), wave tile 64x64.
#define GLOAD_LDS16(gsrc, ldst) \
    __builtin_amdgcn_global_load_lds((const __attribute__((address_space(1))) void*)(gsrc), \
                                     (__attribute__((address_space(3))) void*)(ldst), 16, 0, 0)

__global__ __launch_bounds__(512, 1) void gemm_kernel(
    const ushort_t* __restrict__ Ah,     // [1024][2048] bf16 scaled A
    const ushort_t* __restrict__ Xt,     // [8192][2048] bf16
    const float* __restrict__ ps1, const float* __restrict__ ps2,
    const float* __restrict__ rsA, const float* __restrict__ benc,
    float* __restrict__ out)
{
    __shared__ ushort_t sA[2][2][4096];  // [buf][half][128 rows x 32k] 32 KB
    __shared__ ushort_t sX[2][2][8192];  // [buf][half][256 rows x 32k] 64 KB

    // XCD swizzle: blocks sharing an X strip (same bx) land on one XCD.
    const int flat = blockIdx.x;             // 0..255
    const int xcd  = flat & 7;
    const int j    = flat >> 3;              // 0..31
    const int bx   = xcd + ((j & 3) << 3);   // 0..31 (cols bx*256, batch bx)
    const int by   = j >> 2;                 // 0..7  (rows by*128)
    const int l    = by >> 1;

    const int tid  = threadIdx.x;
    const int lane = tid & 63;
    const int w    = tid >> 6;               // 0..7
    const int wm   = w >> 2;                 // 0..1
    const int wn   = w & 3;                  // 0..3
    const int li   = lane & 31, lg = lane >> 5;

    // staging lane decode: instr 1KB covers 16 rows (8 macro-rows)
    const int mg_l = lane >> 3;                  // macro-row within instr
    const int rh   = (lane >> 2) & 1;            // row parity
    const int kc   = (lane & 3) ^ (mg_l & 3);    // pre-swizzled k-chunk
    const ushort_t* aBase  = Ah + (size_t)(by * 128 + w * 16 + 2 * mg_l + rh) * 2048 + kc * 8;
    const ushort_t* xBase0 = Xt + (size_t)(bx * 256 + w * 32 + 2 * mg_l + rh) * 2048 + kc * 8;
    const ushort_t* xBase1 = xBase0 + (size_t)16 * 2048;

#define STAGE_H(bf_, kt_, h_) do { \
    const int ko_ = (kt_) * 64 + (h_) * 32; \
    GLOAD_LDS16(aBase  + ko_, &sA[bf_][h_][w * 512]); \
    GLOAD_LDS16(xBase0 + ko_, &sX[bf_][h_][w * 1024]); \
    GLOAD_LDS16(xBase1 + ko_, &sX[bf_][h_][w * 1024 + 512]); \
} while (0)

    f32x16 acc[2][2];
#pragma unroll
    for (int mm = 0; mm < 2; ++mm)
#pragma unroll
        for (int nn = 0; nn < 2; ++nn)
#pragma unroll
            for (int rr = 0; rr < 16; ++rr) acc[mm][nn][rr] = 0.0f;

#define PHASE(bf_, h_, STAGEOPS, VMNT) do { \
    const ushort_t* pa_ = &sA[bf_][h_][0]; \
    const ushort_t* px_ = &sX[bf_][h_][0]; \
    bf16x8 af[2][2], xf[2][2]; \
    _Pragma("unroll") \
    for (int s_ = 0; s_ < 2; ++s_) { \
        const int ch_ = (s_ * 2 + lg) ^ ((li >> 1) & 3); \
        _Pragma("unroll") \
        for (int mm_ = 0; mm_ < 2; ++mm_) \
            af[s_][mm_] = *(const bf16x8*)(pa_ + (wm * 32 + mm_ * 16 + (li >> 1)) * 64 + (li & 1) * 32 + ch_ * 8); \
        _Pragma("unroll") \
        for (int nn_ = 0; nn_ < 2; ++nn_) \
            xf[s_][nn_] = *(const bf16x8*)(px_ + (wn * 32 + nn_ * 16 + (li >> 1)) * 64 + (li & 1) * 32 + ch_ * 8); \
    } \
    STAGEOPS; \
    VMNT; \
    asm volatile("" ::: "memory"); \
    __builtin_amdgcn_s_barrier(); \
    __builtin_amdgcn_s_setprio(1); \
    _Pragma("unroll") \
    for (int s_ = 0; s_ < 2; ++s_) \
        _Pragma("unroll") \
        for (int mm_ = 0; mm_ < 2; ++mm_) \
            _Pragma("unroll") \
            for (int nn_ = 0; nn_ < 2; ++nn_) \
                acc[mm_][nn_] = __builtin_amdgcn_mfma_f32_32x32x16_bf16(af[s_][mm_], xf[s_][nn_], acc[mm_][nn_], 0, 0, 0); \
    __builtin_amdgcn_s_setprio(0); \
    asm volatile("" ::: "memory"); \
    __builtin_amdgcn_s_barrier(); \
    asm volatile("" ::: "memory"); \
} while (0)

    // prologue: stage kt0 both halves; wait h0 (h1 stays in flight)
    STAGE_H(0, 0, 0);
    STAGE_H(0, 0, 1);
    asm volatile("s_waitcnt vmcnt(3)" ::: "memory");
    __builtin_amdgcn_s_barrier();
    asm volatile("" ::: "memory");

#pragma unroll 1
    for (int kt = 0; kt < 31; ++kt) {
        const int bf = kt & 1;
        // PA: consume h0; prefetch (kt+1).h0; wait kt.h1 (leave 3 in flight)
        PHASE(bf, 0, STAGE_H(bf ^ 1, kt + 1, 0),
              asm volatile("s_waitcnt vmcnt(3)" ::: "memory"));
        // PB: consume h1; prefetch (kt+1).h1; wait (kt+1).h0 (leave 3 in flight)
        PHASE(bf, 1, STAGE_H(bf ^ 1, kt + 1, 1),
              asm volatile("s_waitcnt vmcnt(3)" ::: "memory"));
    }
    PHASE(1, 0, , asm volatile("s_waitcnt vmcnt(0)" ::: "memory"));
    PHASE(1, 1, , );
#undef PHASE
#undef STAGE_H

    // ---- epilogue: finalize stats for batch bx, then fused affine write ----
    const float be = benc[l];
    float mn[2], sd[2];
#pragma unroll
    for (int nn = 0; nn < 2; ++nn) {
        const int colp = wn * 64 + nn * 32 + li;      // 0..255 (n index; batch = bx)
        float s = 0.f, q = 0.f;
#pragma unroll
        for (int st = 0; st < 32; ++st) {
            s += ps1[(size_t)st * 8192 + bx * 256 + colp];
            q += ps2[(size_t)st * 8192 + bx * 256 + colp];
        }
        const float mean = s * (1.0f / 2048.0f);
        float var = q * (1.0f / 2048.0f) - mean * mean;
        var = fmaxf(var, 0.0f);
        mn[nn] = mean;
        sd[nn] = sqrtf(var + 1e-5f);
    }
#pragma unroll
    for (int mm = 0; mm < 2; ++mm)
#pragma unroll
        for (int nn = 0; nn < 2; ++nn) {
            const int colp = wn * 64 + nn * 32 + li;
            const float ben = be * sd[nn];
#pragma unroll
            for (int rr = 0; rr < 16; ++rr) {
                const int row = by * 128 + wm * 64 + mm * 32 + ((rr & 3) + 8 * (rr >> 2) + 4 * lg);
                out[((size_t)bx * 1024 + row) * 256 + colp] =
                    acc[mm][nn][rr] + mn[nn] * (1.0f - rsA[row]) + ben;
            }
        }
}

// ---------------- launch ----------------
extern "C" void kernel_launch(void* const* d_in, const int* in_sizes, int n_in,
                              void* d_out, int out_size, void* d_ws, size_t ws_size,
                              hipStream_t stream) {
    (void)in_sizes; (void)n_in; (void)out_size; (void)ws_size;
    const float* x_enc  = (const float*)d_in[0];
    const float* W_base = (const float*)d_in[4];
    const float* W_enc  = (const float*)d_in[5];
    const float* b_enc  = (const float*)d_in[6];
    float* out = (float*)d_out;

    char* ws = (char*)d_ws;
    float*    wsP   = (float*)(ws);                  // 11*65536 f32 powers (2.75 MB)
    float*    wsRsA = (float*)(ws + 0x300000);       // 1024 f32
    float*    wsS1  = (float*)(ws + 0x310000);       // 32*8192 f32 (1 MB)
    float*    wsS2  = (float*)(ws + 0x410000);       // 1 MB
    ushort_t* wsAh  = (ushort_t*)(ws + 0x510000);    // 1024*2048 bf16 (4 MB)
    ushort_t* wsXt  = (ushort_t*)(ws + 0x910000);    // [8192][2048] bf16 (32 MB)

    // W^1 into slot 0
    hipMemcpyAsync(wsP, W_base, 256 * 256 * sizeof(float), hipMemcpyDeviceToDevice, stream);

    // powers: slot m-1 = W^m
    { PowOps o{{0, 0, 0, 0}, {0, 0, 0, 0}, {1, 0, 0, 0}};            // W2
      powmul<<<dim3(1, 64), 256, 0, stream>>>(wsP, o); }
    { PowOps o{{1, 1, 0, 0}, {0, 1, 0, 0}, {2, 3, 0, 0}};            // W3,W4
      powmul<<<dim3(2, 64), 256, 0, stream>>>(wsP, o); }
    { PowOps o{{3, 3, 3, 3}, {0, 1, 2, 3}, {4, 5, 6, 7}};            // W5..W8
      powmul<<<dim3(4, 64), 256, 0, stream>>>(wsP, o); }
    { PowOps o{{7, 7, 7, 0}, {0, 1, 2, 0}, {8, 9, 10, 0}};           // W9..W11
      powmul<<<dim3(3, 64), 256, 0, stream>>>(wsP, o); }

    buildA<<<1024, 256, 0, stream>>>(wsP, W_enc, wsAh, wsRsA);
    transpose_stats<<<dim3(32, 4, 32), 256, 0, stream>>>(x_enc, wsXt, wsS1, wsS2);

    gemm_kernel<<<dim3(256), 512, 0, stream>>>(wsAh, wsXt, wsS1, wsS2,
                                               wsRsA, b_enc, out);
}

// Round 7
// 106.769 us; speedup vs baseline: 1.3162x; 1.1049x over previous
//
#include <hip/hip_runtime.h>
#include <cstdint>
#include <cstddef>

// B=32, S=2048, P=256, N=256, K=8, L=4, M_out=1024
// out[b,t,n] = (A @ x_b)[t,n] + mean[b,n]*(1 - rowsumA[t]) + b_enc[t>>8]*std[b,n]
// A[l*256+q, k*256+p] = W_enc[l,k] * (W^(8-k+l))[q,p], materialized bf16 (4MB).
// X = raw x transposed to [b*256+n][s] bf16; normalization affine-folded into
// the GEMM epilogue (mean/std finalized there from partials).
//
// GEMM geometry (R7): 128x128 blocks, grid 512 = 2 blocks/CU, 4 waves (2Mx2N,
// wave 64x64), BK=32, TRIPLE-buffered LDS (48KB/block so both blocks fit),
// counted vmcnt(4) per wave (drain only at tail), ONE barrier per kt.
// LDS macro-row layout (rows of 32 elems): row R, 4-chunk c stored at
//   byte = (R>>1)*128 + (R&1)*64 + ((c ^ ((R>>1)&3))*16   [8 slots, 8 lanes/slot]

typedef unsigned short ushort_t;
typedef unsigned int uint_t;
typedef __attribute__((ext_vector_type(8))) short bf16x8;
typedef __attribute__((ext_vector_type(16))) float f32x16;

__device__ __forceinline__ ushort_t f32_to_bf16(float f) {
    uint_t u = __float_as_uint(f);
    u += 0x7FFFu + ((u >> 16) & 1u);   // RNE (finite values only here)
    return (ushort_t)(u >> 16);
}
__device__ __forceinline__ float bf16_to_f32(ushort_t h) {
    return __uint_as_float((uint_t)h << 16);
}

// ---------------- W powers: C = A * B for up to 4 (slot) triples ----------------
// slot index <0 means the raw W_base input. Slots 0..9 hold W^2..W^11.
struct PowOps { int sa[4]; int sb[4]; int sd[4]; };

__global__ void powmul(const float* __restrict__ Wb, float* __restrict__ Pw, PowOps ops) {
    __shared__ float As[4 * 256];
    const int mat = blockIdx.x;
    const int r0  = blockIdx.y * 4;      // 64 row-blocks of 4
    const int tid = threadIdx.x;         // 256
    const float* A  = (ops.sa[mat] < 0) ? Wb : Pw + (size_t)ops.sa[mat] * 65536;
    const float* Bm = (ops.sb[mat] < 0) ? Wb : Pw + (size_t)ops.sb[mat] * 65536;
    float* C        = Pw + (size_t)ops.sd[mat] * 65536;
#pragma unroll
    for (int i = 0; i < 4; ++i) As[i * 256 + tid] = A[(size_t)(r0 + i) * 256 + tid];
    __syncthreads();
    float a0 = 0.f, a1 = 0.f, a2 = 0.f, a3 = 0.f;
    for (int p = 0; p < 256; p += 8) {
        float bv[8];
#pragma unroll
        for (int u = 0; u < 8; ++u) bv[u] = Bm[(size_t)(p + u) * 256 + tid];
#pragma unroll
        for (int u = 0; u < 8; ++u) {
            a0 += As[0 * 256 + p + u] * bv[u];
            a1 += As[1 * 256 + p + u] * bv[u];
            a2 += As[2 * 256 + p + u] * bv[u];
            a3 += As[3 * 256 + p + u] * bv[u];
        }
    }
    C[(size_t)(r0 + 0) * 256 + tid] = a0;
    C[(size_t)(r0 + 1) * 256 + tid] = a1;
    C[(size_t)(r0 + 2) * 256 + tid] = a2;
    C[(size_t)(r0 + 3) * 256 + tid] = a3;
}

// ---------------- fused prep: transpose+stats (blocks 0..4095) | buildA (4096..5119) ----------------
__global__ void prep(const float* __restrict__ x, ushort_t* __restrict__ Xt,
                     float* __restrict__ ps1, float* __restrict__ ps2,
                     const float* __restrict__ Pw, const float* __restrict__ Wb,
                     const float* __restrict__ Wenc,
                     ushort_t* __restrict__ Ah, float* __restrict__ rsA) {
    __shared__ float lds[64 * 65];
    __shared__ float red1[16 * 64];
    __shared__ float red2[16 * 64];
    const int bid = blockIdx.x;
    const int tid = threadIdx.x;
    if (bid < 4096) {
        // -------- transpose RAW x + bf16 convert + stats partials --------
        const int st = bid & 31;                   // s-tile
        const int nt = (bid >> 5) & 3;             // n-tile
        const int b  = bid >> 7;                   // batch
        const int c = tid & 15, r = tid >> 4;
        const int s0 = st * 64;
        float s1[4] = {0,0,0,0}, s2[4] = {0,0,0,0};
#pragma unroll
        for (int it = 0; it < 4; ++it) {
            const int ii = r + it * 16;
            const float4 v = *(const float4*)(x + ((size_t)b * 2048 + s0 + ii) * 256 + nt * 64 + c * 4);
            const float vv[4] = {v.x, v.y, v.z, v.w};
#pragma unroll
            for (int jj = 0; jj < 4; ++jj) {
                lds[ii * 65 + c * 4 + jj] = vv[jj];
                s1[jj] += vv[jj]; s2[jj] += vv[jj] * vv[jj];
            }
        }
#pragma unroll
        for (int jj = 0; jj < 4; ++jj) { red1[r * 64 + c * 4 + jj] = s1[jj]; red2[r * 64 + c * 4 + jj] = s2[jj]; }
        __syncthreads();
        if (tid < 64) {
            float a = 0.f, q = 0.f;
#pragma unroll
            for (int rr = 0; rr < 16; ++rr) { a += red1[rr * 64 + tid]; q += red2[rr * 64 + tid]; }
            const size_t o = (size_t)st * 8192 + b * 256 + nt * 64 + tid;
            ps1[o] = a; ps2[o] = q;
        }
#pragma unroll
        for (int step = 0; step < 8; ++step) {
            const int npr = step * 8 + (tid >> 5);
            const int sp  = (tid & 31) * 2;
            const float f0 = lds[sp * 65 + npr];
            const float f1 = lds[(sp + 1) * 65 + npr];
            const uint_t packed = (uint_t)f32_to_bf16(f0) | ((uint_t)f32_to_bf16(f1) << 16);
            *(uint_t*)(Xt + ((size_t)b * 256 + nt * 64 + npr) * 2048 + s0 + sp) = packed;
        }
    } else {
        // -------- build scaled A (bf16) + rowsums of the ROUNDED A --------
        const int t = bid - 4096;        // 0..1023
        const int l = t >> 8, q = t & 255;
        const int c = tid;
        float part = 0.f;
#pragma unroll
        for (int k = 0; k < 8; ++k) {
            const int m = 8 - k + l;     // 1..11
            const float* src = (m == 1) ? Wb : (Pw + (size_t)(m - 2) * 65536);
            const float val = Wenc[l * 8 + k] * src[q * 256 + c];
            const ushort_t h = f32_to_bf16(val);
            Ah[(size_t)t * 2048 + k * 256 + c] = h;
            part += bf16_to_f32(h);
        }
#pragma unroll
        for (int off = 32; off > 0; off >>= 1) part += __shfl_xor(part, off);
        if ((c & 63) == 0) red1[c >> 6] = part;
        __syncthreads();
        if (c == 0) rsA[t] = red1[0] + red1[1] + red1[2] + red1[3];
    }
}

// ---------------- GEMM ----------------
#define GLOAD_LDS16(gsrc, ldst) \
    __builtin_amdgcn_global_load_lds((const __attribute__((address_space(1))) void*)(gsrc), \
                                     (__attribute__((address_space(3))) void*)(ldst), 16, 0, 0)

__global__ __launch_bounds__(256, 2) void gemm_kernel(
    const ushort_t* __restrict__ Ah,     // [1024][2048] bf16 scaled A
    const ushort_t* __restrict__ Xt,     // [8192][2048] bf16
    const float* __restrict__ ps1, const float* __restrict__ ps2,
    const float* __restrict__ rsA, const float* __restrict__ benc,
    float* __restrict__ out)
{
    __shared__ ushort_t sA[3][4096];     // 3 bufs x (128 rows x 32k) = 24 KB
    __shared__ ushort_t sX[3][4096];     // 24 KB  -> 48 KB total, 2 blocks/CU

    // XCD swizzle: the 8 blocks sharing an X strip (same bx) land on one XCD.
    const int flat = blockIdx.x;             // 0..511
    const int xcd  = flat & 7;
    const int j    = flat >> 3;              // 0..63
    const int bx   = xcd + ((j & 7) << 3);   // 0..63 (cols bx*128)
    const int by   = j >> 3;                 // 0..7  (rows by*128)
    const int l    = by >> 1;

    const int tid  = threadIdx.x;
    const int lane = tid & 63;
    const int w    = tid >> 6;               // 0..3
    const int wm   = w >> 1, wn = w & 1;
    const int li   = lane & 31, lg = lane >> 5;
    const int lq3  = (li >> 1) & 3;

    // staging lane decode: one 1KB instr covers 16 rows (8 macro-rows)
    const int lrow = 2 * (lane >> 3) + ((lane >> 2) & 1);  // row within instr
    const int kc   = (lane & 3) ^ ((lane >> 3) & 3);       // pre-swizzled chunk
    const ushort_t* aBase0 = Ah + (size_t)(by * 128 + 16 * (2 * w + 0) + lrow) * 2048 + kc * 8;
    const ushort_t* aBase1 = Ah + (size_t)(by * 128 + 16 * (2 * w + 1) + lrow) * 2048 + kc * 8;
    const ushort_t* xBase0 = Xt + (size_t)(bx * 128 + 16 * (2 * w + 0) + lrow) * 2048 + kc * 8;
    const ushort_t* xBase1 = Xt + (size_t)(bx * 128 + 16 * (2 * w + 1) + lrow) * 2048 + kc * 8;

    ushort_t* sAf = &sA[0][0];
    ushort_t* sXf = &sX[0][0];

#define STAGE(dst_off, ko_) do { \
    GLOAD_LDS16(aBase0 + (ko_), sAf + (dst_off) + (2 * w + 0) * 512); \
    GLOAD_LDS16(aBase1 + (ko_), sAf + (dst_off) + (2 * w + 1) * 512); \
    GLOAD_LDS16(xBase0 + (ko_), sXf + (dst_off) + (2 * w + 0) * 512); \
    GLOAD_LDS16(xBase1 + (ko_), sXf + (dst_off) + (2 * w + 1) * 512); \
} while (0)

    f32x16 acc[2][2];
#pragma unroll
    for (int mm = 0; mm < 2; ++mm)
#pragma unroll
        for (int nn = 0; nn < 2; ++nn)
#pragma unroll
            for (int rr = 0; rr < 16; ++rr) acc[mm][nn][rr] = 0.0f;

    // prologue: stage kt=0 -> buf0, kt=1 -> buf1 (8 loads/wave in flight)
    STAGE(0, 0);
    STAGE(4096, 32);

    int cb = 0;
#pragma unroll 1
    for (int kt = 0; kt < 64; ++kt) {
        if (kt < 63) { asm volatile("s_waitcnt vmcnt(4)" ::: "memory"); }
        else         { asm volatile("s_waitcnt vmcnt(0)" ::: "memory"); }
        __builtin_amdgcn_s_barrier();
        asm volatile("" ::: "memory");

        const ushort_t* pa = sAf + cb * 4096;
        const ushort_t* px = sXf + cb * 4096;
        bf16x8 af[2][2], xf[2][2];
#pragma unroll
        for (int ks = 0; ks < 2; ++ks) {
            const int sl = ((ks << 1) + lg) ^ lq3;
            const int ro = (li >> 1) * 64 + (li & 1) * 32 + sl * 8;
            af[ks][0] = *(const bf16x8*)(pa + wm * 2048 + ro);
            af[ks][1] = *(const bf16x8*)(pa + wm * 2048 + 1024 + ro);
            xf[ks][0] = *(const bf16x8*)(px + wn * 2048 + ro);
            xf[ks][1] = *(const bf16x8*)(px + wn * 2048 + 1024 + ro);
        }
        if (kt < 62) {
            const int sb_ = (cb >= 1) ? cb - 1 : 2;    // (cb+2)%3
            STAGE(sb_ * 4096, (kt + 2) * 32);
        }
        __builtin_amdgcn_s_setprio(1);
#pragma unroll
        for (int ks = 0; ks < 2; ++ks) {
            acc[0][0] = __builtin_amdgcn_mfma_f32_32x32x16_bf16(af[ks][0], xf[ks][0], acc[0][0], 0, 0, 0);
            acc[0][1] = __builtin_amdgcn_mfma_f32_32x32x16_bf16(af[ks][0], xf[ks][1], acc[0][1], 0, 0, 0);
            acc[1][0] = __builtin_amdgcn_mfma_f32_32x32x16_bf16(af[ks][1], xf[ks][0], acc[1][0], 0, 0, 0);
            acc[1][1] = __builtin_amdgcn_mfma_f32_32x32x16_bf16(af[ks][1], xf[ks][1], acc[1][1], 0, 0, 0);
        }
        __builtin_amdgcn_s_setprio(0);
        asm volatile("" ::: "memory");
        cb = (cb == 2) ? 0 : cb + 1;
    }
#undef STAGE

    // ---- epilogue: finalize stats per column, fused affine write ----
    const float be = benc[l];
    float mn[2], sd[2];
#pragma unroll
    for (int nn = 0; nn < 2; ++nn) {
        const int col = bx * 128 + wn * 64 + nn * 32 + li;   // 0..8191 (= b*256+n)
        float s = 0.f, q = 0.f;
#pragma unroll
        for (int st = 0; st < 32; ++st) {
            s += ps1[(size_t)st * 8192 + col];
            q += ps2[(size_t)st * 8192 + col];
        }
        const float mean = s * (1.0f / 2048.0f);
        float var = q * (1.0f / 2048.0f) - mean * mean;
        var = fmaxf(var, 0.0f);
        mn[nn] = mean;
        sd[nn] = sqrtf(var + 1e-5f);
    }
#pragma unroll
    for (int mm = 0; mm < 2; ++mm)
#pragma unroll
        for (int nn = 0; nn < 2; ++nn) {
            const int col = bx * 128 + wn * 64 + nn * 32 + li;
            const int bq = col >> 8, nq = col & 255;
            const float ben = be * sd[nn];
#pragma unroll
            for (int rr = 0; rr < 16; ++rr) {
                const int row = by * 128 + wm * 64 + mm * 32 + ((rr & 3) + 8 * (rr >> 2) + 4 * lg);
                out[((size_t)bq * 1024 + row) * 256 + nq] =
                    acc[mm][nn][rr] + mn[nn] * (1.0f - rsA[row]) + ben;
            }
        }
}

// ---------------- launch ----------------
extern "C" void kernel_launch(void* const* d_in, const int* in_sizes, int n_in,
                              void* d_out, int out_size, void* d_ws, size_t ws_size,
                              hipStream_t stream) {
    (void)in_sizes; (void)n_in; (void)out_size; (void)ws_size;
    const float* x_enc  = (const float*)d_in[0];
    const float* W_base = (const float*)d_in[4];
    const float* W_enc  = (const float*)d_in[5];
    const float* b_enc  = (const float*)d_in[6];
    float* out = (float*)d_out;

    char* ws = (char*)d_ws;
    float*    wsP   = (float*)(ws);                  // 10*65536 f32 (W^2..W^11)
    float*    wsRsA = (float*)(ws + 0x300000);       // 1024 f32
    float*    wsS1  = (float*)(ws + 0x310000);       // 32*8192 f32 (1 MB)
    float*    wsS2  = (float*)(ws + 0x410000);       // 1 MB
    ushort_t* wsAh  = (ushort_t*)(ws + 0x510000);    // 1024*2048 bf16 (4 MB)
    ushort_t* wsXt  = (ushort_t*)(ws + 0x910000);    // [8192][2048] bf16 (32 MB)

    // power chain: slots 0..9 = W^2..W^11 (slot<0 in PowOps = W_base)
    { PowOps o{{-1, 0, 0, 0}, {-1, 0, 0, 0}, {0, 0, 0, 0}};          // W2
      powmul<<<dim3(1, 64), 256, 0, stream>>>(W_base, wsP, o); }
    { PowOps o{{0, 0, 0, 0}, {-1, 0, 0, 0}, {1, 2, 0, 0}};           // W3=W2*W, W4=W2*W2
      powmul<<<dim3(2, 64), 256, 0, stream>>>(W_base, wsP, o); }
    { PowOps o{{2, 2, 2, 2}, {-1, 0, 1, 2}, {3, 4, 5, 6}};           // W5..W8 (from W4)
      powmul<<<dim3(4, 64), 256, 0, stream>>>(W_base, wsP, o); }
    { PowOps o{{6, 6, 6, 0}, {-1, 0, 1, 0}, {7, 8, 9, 0}};           // W9..W11 (from W8)
      powmul<<<dim3(3, 64), 256, 0, stream>>>(W_base, wsP, o); }

    prep<<<5120, 256, 0, stream>>>(x_enc, wsXt, wsS1, wsS2, wsP, W_base, W_enc,
                                   wsAh, wsRsA);

    gemm_kernel<<<512, 256, 0, stream>>>(wsAh, wsXt, wsS1, wsS2, wsRsA, b_enc, out);
}

// Round 8
// 98.766 us; speedup vs baseline: 1.4228x; 1.0810x over previous
//
#include <hip/hip_runtime.h>
#include <cstdint>
#include <cstddef>

// B=32, S=2048, P=256, N=256, K=8, L=4, M_out=1024
// Factorized: v_k = bf16(W^{8-k}) @ X        (stage 1, 8.6 GF)
//             c_l = sum_k W_enc[l,k] v_k     (streaming combine)
//             dec[l] = bf16(W^l) @ c_l       (stage 2, 4.3 GF; W^0 = I exact)
// out = dec + mean*(1-rowsumA) + b_enc*std  (affine fold; rowsumA from rounded maps)

typedef unsigned short ushort_t;
typedef unsigned int uint_t;
typedef __attribute__((ext_vector_type(8))) short bf16x8;
typedef __attribute__((ext_vector_type(16))) float f32x16;

__device__ __forceinline__ ushort_t f32_to_bf16(float f) {
    uint_t u = __float_as_uint(f);
    u += 0x7FFFu + ((u >> 16) & 1u);   // RNE
    return (ushort_t)(u >> 16);
}
__device__ __forceinline__ float bf16_to_f32(ushort_t h) {
    return __uint_as_float((uint_t)h << 16);
}

// ---------------- W powers: C = A * B, slots 0..6 = W^2..W^8 (idx<0 -> W_base) ----------------
struct PowOps { int sa[4]; int sb[4]; int sd[4]; };

__global__ void powmul(const float* __restrict__ Wb, float* __restrict__ Pw, PowOps ops) {
    __shared__ float As[4 * 256];
    const int mat = blockIdx.x;
    const int r0  = blockIdx.y * 4;
    const int tid = threadIdx.x;
    const float* A  = (ops.sa[mat] < 0) ? Wb : Pw + (size_t)ops.sa[mat] * 65536;
    const float* Bm = (ops.sb[mat] < 0) ? Wb : Pw + (size_t)ops.sb[mat] * 65536;
    float* C        = Pw + (size_t)ops.sd[mat] * 65536;
#pragma unroll
    for (int i = 0; i < 4; ++i) As[i * 256 + tid] = A[(size_t)(r0 + i) * 256 + tid];
    __syncthreads();
    float a0 = 0.f, a1 = 0.f, a2 = 0.f, a3 = 0.f;
    for (int p = 0; p < 256; p += 8) {
        float bv[8];
#pragma unroll
        for (int u = 0; u < 8; ++u) bv[u] = Bm[(size_t)(p + u) * 256 + tid];
#pragma unroll
        for (int u = 0; u < 8; ++u) {
            a0 += As[0 * 256 + p + u] * bv[u];
            a1 += As[1 * 256 + p + u] * bv[u];
            a2 += As[2 * 256 + p + u] * bv[u];
            a3 += As[3 * 256 + p + u] * bv[u];
        }
    }
    C[(size_t)(r0 + 0) * 256 + tid] = a0;
    C[(size_t)(r0 + 1) * 256 + tid] = a1;
    C[(size_t)(r0 + 2) * 256 + tid] = a2;
    C[(size_t)(r0 + 3) * 256 + tid] = a3;
}

// ---------------- prep: transpose+stats (0..4095) | bf16 powers + rowsums (4096..4131) ----------------
// Pb slots by exponent e=0..8: Pb[0]=I, Pb[1]=bf16(W), Pb[e]=bf16(W^e). prs[e][q]=rowsum(Pb[e]).
__global__ void prep(const float* __restrict__ x, ushort_t* __restrict__ Xt,
                     float* __restrict__ ps1, float* __restrict__ ps2,
                     const float* __restrict__ Pw, const float* __restrict__ Wb,
                     ushort_t* __restrict__ Pb, float* __restrict__ prs) {
    __shared__ float lds[64 * 65];
    __shared__ float red1[16 * 64];
    __shared__ float red2[16 * 64];
    const int bid = blockIdx.x;
    const int tid = threadIdx.x;
    if (bid < 4096) {
        const int st = bid & 31;
        const int nt = (bid >> 5) & 3;
        const int b  = bid >> 7;
        const int c = tid & 15, r = tid >> 4;
        const int s0 = st * 64;
        float s1[4] = {0,0,0,0}, s2[4] = {0,0,0,0};
#pragma unroll
        for (int it = 0; it < 4; ++it) {
            const int ii = r + it * 16;
            const float4 v = *(const float4*)(x + ((size_t)b * 2048 + s0 + ii) * 256 + nt * 64 + c * 4);
            const float vv[4] = {v.x, v.y, v.z, v.w};
#pragma unroll
            for (int jj = 0; jj < 4; ++jj) {
                lds[ii * 65 + c * 4 + jj] = vv[jj];
                s1[jj] += vv[jj]; s2[jj] += vv[jj] * vv[jj];
            }
        }
#pragma unroll
        for (int jj = 0; jj < 4; ++jj) { red1[r * 64 + c * 4 + jj] = s1[jj]; red2[r * 64 + c * 4 + jj] = s2[jj]; }
        __syncthreads();
        if (tid < 64) {
            float a = 0.f, q = 0.f;
#pragma unroll
            for (int rr = 0; rr < 16; ++rr) { a += red1[rr * 64 + tid]; q += red2[rr * 64 + tid]; }
            const size_t o = (size_t)st * 8192 + b * 256 + nt * 64 + tid;
            ps1[o] = a; ps2[o] = q;
        }
#pragma unroll
        for (int step = 0; step < 8; ++step) {
            const int npr = step * 8 + (tid >> 5);
            const int sp  = (tid & 31) * 2;
            const float f0 = lds[sp * 65 + npr];
            const float f1 = lds[(sp + 1) * 65 + npr];
            const uint_t packed = (uint_t)f32_to_bf16(f0) | ((uint_t)f32_to_bf16(f1) << 16);
            *(uint_t*)(Xt + ((size_t)b * 256 + nt * 64 + npr) * 2048 + s0 + sp) = packed;
        }
    } else {
        const int ib = bid - 4096;           // 0..35
        const int e  = ib >> 2;              // exponent 0..8
        const int rq = ib & 3;
        const int q  = rq * 64 + (tid >> 2);
        const int cc = tid & 3;
        uint2* dst = (uint2*)(Pb + (size_t)e * 65536 + q * 256 + cc * 64);
        float s = 0.f;
        if (e == 0) {
#pragma unroll
            for (int i = 0; i < 16; ++i) {
                uint2 o; o.x = 0u; o.y = 0u;
                const int col0 = cc * 64 + i * 4;
                if (q >= col0 && q < col0 + 4) {
                    const int j = q - col0;
                    if (j == 0) o.x = 0x3F80u; else if (j == 1) o.x = 0x3F800000u;
                    else if (j == 2) o.y = 0x3F80u; else o.y = 0x3F800000u;
                }
                dst[i] = o;
            }
            s = 1.0f;
        } else {
            const float* src = (e == 1) ? Wb : (Pw + (size_t)(e - 2) * 65536);
            const float4* sp = (const float4*)(src + (size_t)q * 256 + cc * 64);
#pragma unroll
            for (int i = 0; i < 16; ++i) {
                const float4 v = sp[i];
                const ushort_t h0 = f32_to_bf16(v.x), h1 = f32_to_bf16(v.y);
                const ushort_t h2 = f32_to_bf16(v.z), h3 = f32_to_bf16(v.w);
                s += bf16_to_f32(h0) + bf16_to_f32(h1) + bf16_to_f32(h2) + bf16_to_f32(h3);
                uint2 o; o.x = (uint_t)h0 | ((uint_t)h1 << 16); o.y = (uint_t)h2 | ((uint_t)h3 << 16);
                dst[i] = o;
            }
        }
        s += __shfl_xor(s, 1);
        s += __shfl_xor(s, 2);
        if (cc == 0) prs[e * 256 + q] = s;
    }
}

// ---------------- stage-1 GEMM: vt[k][col][q] = (Xt_colslice @ Pb[8-k]^T) ----------------
// + finalize blocks (512..547): meanv/stdv (32) and rsA (4).
#define GLOAD_LDS16(gsrc, ldst) \
    __builtin_amdgcn_global_load_lds((const __attribute__((address_space(1))) void*)(gsrc), \
                                     (__attribute__((address_space(3))) void*)(ldst), 16, 0, 0)

__global__ __launch_bounds__(256, 2) void gemm_v(
    const ushort_t* __restrict__ Pb,     // 9*65536 bf16 (e=0..8)
    const ushort_t* __restrict__ Xt,     // [8192][2048] bf16
    ushort_t* __restrict__ vt,           // [8][8192][256] bf16
    const float* __restrict__ ps1, const float* __restrict__ ps2,
    const float* __restrict__ prs, const float* __restrict__ Wenc,
    float* __restrict__ meanv, float* __restrict__ stdv, float* __restrict__ rsA)
{
    __shared__ ushort_t sAa[3][4096];    // A = Xt tile [128 rows x 32k] x3 (24 KB)
    __shared__ ushort_t sBb[3][8192];    // B = power tile [256 rows x 32k] x3 (48 KB)

    const int bid = blockIdx.x;
    const int tid = threadIdx.x;
    if (bid >= 512) {
        // ---- finalize ----
        const int idx = bid - 512;       // 0..35
        if (idx < 32) {
            const int b = idx;
            float s = 0.f, q = 0.f;
#pragma unroll
            for (int st = 0; st < 32; ++st) {
                s += ps1[(size_t)st * 8192 + b * 256 + tid];
                q += ps2[(size_t)st * 8192 + b * 256 + tid];
            }
            const float mean = s * (1.0f / 2048.0f);
            float var = q * (1.0f / 2048.0f) - mean * mean;
            var = fmaxf(var, 0.0f);
            meanv[b * 256 + tid] = mean;
            stdv [b * 256 + tid] = sqrtf(var + 1e-5f);
        } else {
            const int l = idx - 32;
            float u = 0.f;
#pragma unroll
            for (int k = 0; k < 8; ++k) u += Wenc[l * 8 + k] * prs[(8 - k) * 256 + tid];
            float* uf = (float*)&sAa[0][0];
            uf[tid] = u;
            __syncthreads();
            const uint2* rp = (const uint2*)(Pb + (size_t)l * 65536 + tid * 256);
            float s = 0.f;
#pragma unroll
            for (int i = 0; i < 64; ++i) {
                const uint2 v = rp[i];
                s += bf16_to_f32((ushort_t)(v.x & 0xffff)) * uf[i * 4 + 0]
                   + bf16_to_f32((ushort_t)(v.x >> 16))    * uf[i * 4 + 1]
                   + bf16_to_f32((ushort_t)(v.y & 0xffff)) * uf[i * 4 + 2]
                   + bf16_to_f32((ushort_t)(v.y >> 16))    * uf[i * 4 + 3];
            }
            rsA[l * 256 + tid] = s;
        }
        return;
    }

    // ---- GEMM blocks: grid 512 = 8 xcd x 8 colT-group x 8 k ----
    const int xcd  = bid & 7;
    const int g    = bid >> 3;
    const int colT = xcd + ((g & 7) << 3);   // 0..63 (128 Xt rows each)
    const int k    = g >> 3;                 // 0..7
    const int e    = 8 - k;

    const int lane = tid & 63;
    const int w    = tid >> 6;               // 0..3
    const int wm   = w >> 1, wn = w & 1;
    const int li   = lane & 31, lg = lane >> 5;
    const int lq3  = (li >> 1) & 3;
    const int lrow = 2 * (lane >> 3) + ((lane >> 2) & 1);
    const int kc   = (lane & 3) ^ ((lane >> 3) & 3);

    const ushort_t* xtb = Xt + (size_t)(colT * 128) * 2048 + k * 256;  // + row*2048 + p
    const ushort_t* pbb = Pb + (size_t)e * 65536;                      // + q*256 + p

#define VSTAGE(bf_, kt_) do { \
    const int p0_ = (kt_) * 32 + kc * 8; \
    GLOAD_LDS16(xtb + (size_t)(w * 32 + 0  + lrow) * 2048 + p0_, &sAa[bf_][(w * 32 + 0)  * 32]); \
    GLOAD_LDS16(xtb + (size_t)(w * 32 + 16 + lrow) * 2048 + p0_, &sAa[bf_][(w * 32 + 16) * 32]); \
    GLOAD_LDS16(pbb + (w * 64 + 0  + lrow) * 256 + p0_, &sBb[bf_][(w * 64 + 0)  * 32]); \
    GLOAD_LDS16(pbb + (w * 64 + 16 + lrow) * 256 + p0_, &sBb[bf_][(w * 64 + 16) * 32]); \
    GLOAD_LDS16(pbb + (w * 64 + 32 + lrow) * 256 + p0_, &sBb[bf_][(w * 64 + 32) * 32]); \
    GLOAD_LDS16(pbb + (w * 64 + 48 + lrow) * 256 + p0_, &sBb[bf_][(w * 64 + 48) * 32]); \
} while (0)

    f32x16 acc[2][4];
#pragma unroll
    for (int mm = 0; mm < 2; ++mm)
#pragma unroll
        for (int nn = 0; nn < 4; ++nn)
#pragma unroll
            for (int rr = 0; rr < 16; ++rr) acc[mm][nn][rr] = 0.0f;

    VSTAGE(0, 0);
    VSTAGE(1, 1);

#define VKT(kt_) do { \
    if ((kt_) < 7) { asm volatile("s_waitcnt vmcnt(6)" ::: "memory"); } \
    else           { asm volatile("s_waitcnt vmcnt(0)" ::: "memory"); } \
    __builtin_amdgcn_s_barrier(); \
    asm volatile("" ::: "memory"); \
    const ushort_t* pa_ = &sAa[(kt_) % 3][0]; \
    const ushort_t* px_ = &sBb[(kt_) % 3][0]; \
    bf16x8 af[2][2], xf[2][4]; \
    _Pragma("unroll") \
    for (int ks = 0; ks < 2; ++ks) { \
        const int sl = ((ks << 1) + lg) ^ lq3; \
        const int ro = (li >> 1) * 64 + (li & 1) * 32 + sl * 8; \
        af[ks][0] = *(const bf16x8*)(pa_ + wm * 2048 + ro); \
        af[ks][1] = *(const bf16x8*)(pa_ + wm * 2048 + 1024 + ro); \
        xf[ks][0] = *(const bf16x8*)(px_ + wn * 4096 + ro); \
        xf[ks][1] = *(const bf16x8*)(px_ + wn * 4096 + 1024 + ro); \
        xf[ks][2] = *(const bf16x8*)(px_ + wn * 4096 + 2048 + ro); \
        xf[ks][3] = *(const bf16x8*)(px_ + wn * 4096 + 3072 + ro); \
    } \
    if ((kt_) < 6) { VSTAGE(((kt_) + 2) % 3, (kt_) + 2); } \
    __builtin_amdgcn_s_setprio(1); \
    _Pragma("unroll") \
    for (int ks = 0; ks < 2; ++ks) \
        _Pragma("unroll") \
        for (int mm = 0; mm < 2; ++mm) \
            _Pragma("unroll") \
            for (int nn = 0; nn < 4; ++nn) \
                acc[mm][nn] = __builtin_amdgcn_mfma_f32_32x32x16_bf16(af[ks][mm], xf[ks][nn], acc[mm][nn], 0, 0, 0); \
    __builtin_amdgcn_s_setprio(0); \
    asm volatile("" ::: "memory"); \
} while (0)

    VKT(0); VKT(1); VKT(2); VKT(3); VKT(4); VKT(5); VKT(6); VKT(7);
#undef VKT
#undef VSTAGE

    // epilogue: vt[k][col][q] bf16 (lane li = q -> contiguous 64B stores)
    ushort_t* vb = vt + (size_t)k * 2097152;
#pragma unroll
    for (int mm = 0; mm < 2; ++mm)
#pragma unroll
        for (int nn = 0; nn < 4; ++nn) {
            const int q = wn * 128 + nn * 32 + li;
#pragma unroll
            for (int rr = 0; rr < 16; ++rr) {
                const int c = colT * 128 + wm * 64 + mm * 32 + ((rr & 3) + 8 * (rr >> 2) + 4 * lg);
                vb[(size_t)c * 256 + q] = f32_to_bf16(acc[mm][nn][rr]);
            }
        }
}

// ---------------- combine: c[l][col][q] = sum_k we[l,k] vt[k][col][q] ----------------
__global__ void combine(const ushort_t* __restrict__ vt, const float* __restrict__ Wenc,
                        ushort_t* __restrict__ c) {
    const int t   = threadIdx.x;
    const int col = blockIdx.x * 8 + (t >> 5);
    const size_t off = (size_t)col * 256 + (t & 31) * 8;
    float a0[8] = {0,0,0,0,0,0,0,0}, a1[8] = {0,0,0,0,0,0,0,0};
    float a2[8] = {0,0,0,0,0,0,0,0}, a3[8] = {0,0,0,0,0,0,0,0};
#pragma unroll
    for (int k = 0; k < 8; ++k) {
        const bf16x8 v = *(const bf16x8*)(vt + (size_t)k * 2097152 + off);
        const float w0 = Wenc[0 * 8 + k], w1 = Wenc[1 * 8 + k];
        const float w2 = Wenc[2 * 8 + k], w3 = Wenc[3 * 8 + k];
#pragma unroll
        for (int j = 0; j < 8; ++j) {
            const float f = bf16_to_f32((ushort_t)v[j]);
            a0[j] += w0 * f; a1[j] += w1 * f; a2[j] += w2 * f; a3[j] += w3 * f;
        }
    }
    bf16x8 o0, o1, o2, o3;
#pragma unroll
    for (int j = 0; j < 8; ++j) {
        o0[j] = (short)f32_to_bf16(a0[j]); o1[j] = (short)f32_to_bf16(a1[j]);
        o2[j] = (short)f32_to_bf16(a2[j]); o3[j] = (short)f32_to_bf16(a3[j]);
    }
    *(bf16x8*)(c + 0 * 2097152 + off) = o0;
    *(bf16x8*)(c + 1 * 2097152 + off) = o1;
    *(bf16x8*)(c + 2 * 2097152 + off) = o2;
    *(bf16x8*)(c + 3 * 2097152 + off) = o3;
}

// ---------------- stage-2 GEMM: out rows l*256+q' = Pb[l] @ c_l, affine epilogue ----------------
__global__ __launch_bounds__(256, 2) void gemm2(
    const ushort_t* __restrict__ Pb, const ushort_t* __restrict__ c,
    const float* __restrict__ meanv, const float* __restrict__ stdv,
    const float* __restrict__ rsA, const float* __restrict__ benc,
    float* __restrict__ out)
{
    __shared__ ushort_t sAa[3][4096];    // A = Pb[l] tile [128 x 32]
    __shared__ ushort_t sBb[3][4096];    // B = c tile [128 x 32]

    const int bid  = blockIdx.x;         // 0..511
    const int xcd  = bid & 7;
    const int g    = bid >> 3;
    const int colT = xcd + ((g & 7) << 3);   // 0..63
    const int rest = g >> 3;                 // 0..7
    const int l    = rest >> 1;
    const int qpT  = rest & 1;

    const int tid  = threadIdx.x;
    const int lane = tid & 63;
    const int w    = tid >> 6;
    const int wm   = w >> 1, wn = w & 1;
    const int li   = lane & 31, lg = lane >> 5;
    const int lq3  = (li >> 1) & 3;
    const int lrow = 2 * (lane >> 3) + ((lane >> 2) & 1);
    const int kc   = (lane & 3) ^ ((lane >> 3) & 3);

    const ushort_t* ab = Pb + (size_t)l * 65536 + (size_t)(qpT * 128) * 256;      // + r*256 + q
    const ushort_t* cb = c + ((size_t)l * 8192 + colT * 128) * 256;               // + r*256 + q

#define GSTAGE(bf_, kt_) do { \
    const int p0_ = (kt_) * 32 + kc * 8; \
    GLOAD_LDS16(ab + (w * 32 + 0  + lrow) * 256 + p0_, &sAa[bf_][(w * 32 + 0)  * 32]); \
    GLOAD_LDS16(ab + (w * 32 + 16 + lrow) * 256 + p0_, &sAa[bf_][(w * 32 + 16) * 32]); \
    GLOAD_LDS16(cb + (w * 32 + 0  + lrow) * 256 + p0_, &sBb[bf_][(w * 32 + 0)  * 32]); \
    GLOAD_LDS16(cb + (w * 32 + 16 + lrow) * 256 + p0_, &sBb[bf_][(w * 32 + 16) * 32]); \
} while (0)

    f32x16 acc[2][2];
#pragma unroll
    for (int mm = 0; mm < 2; ++mm)
#pragma unroll
        for (int nn = 0; nn < 2; ++nn)
#pragma unroll
            for (int rr = 0; rr < 16; ++rr) acc[mm][nn][rr] = 0.0f;

    GSTAGE(0, 0);
    GSTAGE(1, 1);

#define GKT(kt_) do { \
    if ((kt_) < 7) { asm volatile("s_waitcnt vmcnt(4)" ::: "memory"); } \
    else           { asm volatile("s_waitcnt vmcnt(0)" ::: "memory"); } \
    __builtin_amdgcn_s_barrier(); \
    asm volatile("" ::: "memory"); \
    const ushort_t* pa_ = &sAa[(kt_) % 3][0]; \
    const ushort_t* px_ = &sBb[(kt_) % 3][0]; \
    bf16x8 af[2][2], xf[2][2]; \
    _Pragma("unroll") \
    for (int ks = 0; ks < 2; ++ks) { \
        const int sl = ((ks << 1) + lg) ^ lq3; \
        const int ro = (li >> 1) * 64 + (li & 1) * 32 + sl * 8; \
        af[ks][0] = *(const bf16x8*)(pa_ + wm * 2048 + ro); \
        af[ks][1] = *(const bf16x8*)(pa_ + wm * 2048 + 1024 + ro); \
        xf[ks][0] = *(const bf16x8*)(px_ + wn * 2048 + ro); \
        xf[ks][1] = *(const bf16x8*)(px_ + wn * 2048 + 1024 + ro); \
    } \
    if ((kt_) < 6) { GSTAGE(((kt_) + 2) % 3, (kt_) + 2); } \
    __builtin_amdgcn_s_setprio(1); \
    _Pragma("unroll") \
    for (int ks = 0; ks < 2; ++ks) { \
        acc[0][0] = __builtin_amdgcn_mfma_f32_32x32x16_bf16(af[ks][0], xf[ks][0], acc[0][0], 0, 0, 0); \
        acc[0][1] = __builtin_amdgcn_mfma_f32_32x32x16_bf16(af[ks][0], xf[ks][1], acc[0][1], 0, 0, 0); \
        acc[1][0] = __builtin_amdgcn_mfma_f32_32x32x16_bf16(af[ks][1], xf[ks][0], acc[1][0], 0, 0, 0); \
        acc[1][1] = __builtin_amdgcn_mfma_f32_32x32x16_bf16(af[ks][1], xf[ks][1], acc[1][1], 0, 0, 0); \
    } \
    __builtin_amdgcn_s_setprio(0); \
    asm volatile("" ::: "memory"); \
} while (0)

    GKT(0); GKT(1); GKT(2); GKT(3); GKT(4); GKT(5); GKT(6); GKT(7);
#undef GKT
#undef GSTAGE

    // epilogue: out = acc + mean*(1-rsA) + benc[l]*std
    const float be = benc[l];
    float mn[2], sd[2];
#pragma unroll
    for (int nn = 0; nn < 2; ++nn) {
        const int col = colT * 128 + wn * 64 + nn * 32 + li;
        mn[nn] = meanv[col];
        sd[nn] = stdv [col];
    }
#pragma unroll
    for (int mm = 0; mm < 2; ++mm)
#pragma unroll
        for (int nn = 0; nn < 2; ++nn) {
            const int col = colT * 128 + wn * 64 + nn * 32 + li;
            const int bq = col >> 8, nq = col & 255;
            const float ben = be * sd[nn];
#pragma unroll
            for (int rr = 0; rr < 16; ++rr) {
                const int trow = l * 256 + qpT * 128 + wm * 64 + mm * 32
                               + ((rr & 3) + 8 * (rr >> 2) + 4 * lg);
                out[((size_t)bq * 1024 + trow) * 256 + nq] =
                    acc[mm][nn][rr] + mn[nn] * (1.0f - rsA[trow]) + ben;
            }
        }
}

// ---------------- launch ----------------
extern "C" void kernel_launch(void* const* d_in, const int* in_sizes, int n_in,
                              void* d_out, int out_size, void* d_ws, size_t ws_size,
                              hipStream_t stream) {
    (void)in_sizes; (void)n_in; (void)out_size; (void)ws_size;
    const float* x_enc  = (const float*)d_in[0];
    const float* W_base = (const float*)d_in[4];
    const float* W_enc  = (const float*)d_in[5];
    const float* b_enc  = (const float*)d_in[6];
    float* out = (float*)d_out;

    char* ws = (char*)d_ws;
    float*    wsP    = (float*)(ws);                  // 7*65536 f32 (W^2..W^8)
    ushort_t* wsPb   = (ushort_t*)(ws + 0x200000);    // 9*65536 bf16 (I, W^1..W^8)
    float*    wsPrs  = (float*)(ws + 0x320000);       // 9*256 f32
    float*    wsS1   = (float*)(ws + 0x330000);       // 32*8192 f32
    float*    wsS2   = (float*)(ws + 0x430000);
    float*    wsMean = (float*)(ws + 0x530000);       // 8192 f32
    float*    wsStd  = (float*)(ws + 0x540000);
    float*    wsRsA  = (float*)(ws + 0x550000);       // 1024 f32
    ushort_t* wsXt   = (ushort_t*)(ws + 0x600000);    // [8192][2048] bf16 (32 MB)
    ushort_t* wsC    = (ushort_t*)(ws + 0x600000);    // c aliases Xt (dead after gemm_v)
    ushort_t* wsVt   = (ushort_t*)(ws + 0x2600000);   // [8][8192][256] bf16 (33.5 MB)

    // powers: slots 0..6 = W^2..W^8 (idx<0 = W_base)
    { PowOps o{{-1, 0, 0, 0}, {-1, 0, 0, 0}, {0, 0, 0, 0}};          // W2
      powmul<<<dim3(1, 64), 256, 0, stream>>>(W_base, wsP, o); }
    { PowOps o{{0, 0, 0, 0}, {-1, 0, 0, 0}, {1, 2, 0, 0}};           // W3, W4
      powmul<<<dim3(2, 64), 256, 0, stream>>>(W_base, wsP, o); }
    { PowOps o{{2, 2, 2, 2}, {-1, 0, 1, 2}, {3, 4, 5, 6}};           // W5..W8
      powmul<<<dim3(4, 64), 256, 0, stream>>>(W_base, wsP, o); }

    prep<<<4132, 256, 0, stream>>>(x_enc, wsXt, wsS1, wsS2, wsP, W_base, wsPb, wsPrs);

    gemm_v<<<548, 256, 0, stream>>>(wsPb, wsXt, wsVt, wsS1, wsS2, wsPrs, W_enc,
                                    wsMean, wsStd, wsRsA);

    combine<<<1024, 256, 0, stream>>>(wsVt, W_enc, wsC);

    gemm2<<<512, 256, 0, stream>>>(wsPb, wsC, wsMean, wsStd, wsRsA, b_enc, out);
}